// Round 2
// baseline (421.203 us; speedup 1.0000x reference)
//
#include <hip/hip_runtime.h>
#include <hip/hip_fp16.h>

// ---------------- legacy fused-scan constants (fallback path) ----------------
#define PARTS 5
#define NPP 40960                  // 5*40960 = 204800 >= 200000
#define PADDED_N 204800            // == PARTS*NPP == P2*NPP2
#define NXCD 8
#define GRP 6
#define NCHUNKS (NXCD * GRP)       // 48
#define TPB_SCAN 1024

// ---------------- binned path constants ----------------
#define P2 10                      // dst partitions
#define NPP2 20480                 // nodes per partition; 10*20480 = 204800
#define KSLICES 32                 // slices (blocks) per partition
#define TPB_PREP 512
#define EPT 8                      // edges per thread in prep
#define PREP_EDGES (TPB_PREP * EPT)  // 4096 edges per prep block
#define TPB_SCAN2 1024

typedef int            vint4    __attribute__((ext_vector_type(4)));
typedef float          vfloat4  __attribute__((ext_vector_type(4)));
typedef unsigned short vushort4 __attribute__((ext_vector_type(4)));

// ---------------- Phase 0: W f32 -> f16 (2MB table => L2-resident gathers) ----
// Also zeroes the bucket counters for the binned path (ws re-poisoned each launch).
__global__ __launch_bounds__(256) void wconv_kernel(
    const float* __restrict__ W, __half* __restrict__ Wh, int n,
    int* __restrict__ gcnt)
{
    if (gcnt != nullptr && blockIdx.x == 0 && threadIdx.x < P2)
        gcnt[threadIdx.x] = 0;
    int i4 = (blockIdx.x * 256 + threadIdx.x) * 4;
    if (i4 + 3 < n) {
        vfloat4 w = *reinterpret_cast<const vfloat4*>(W + i4);
        __half2 h01 = __floats2half2_rn(w.x, w.y);
        __half2 h23 = __floats2half2_rn(w.z, w.w);
        *reinterpret_cast<__half2*>(Wh + i4)     = h01;
        *reinterpret_cast<__half2*>(Wh + i4 + 2) = h23;
    } else {
        for (; i4 < n; ++i4) Wh[i4] = __float2half(W[i4]);
    }
}

// ---------------- Phase 1: per-edge msg compute + counting-sort into P2 buckets
// Each block: 4096 edges, read ONCE (vs 5x in the old fused design). Gathers
// (Wh, x) are dense (all lanes); the LDS histogram doesn't depend on them, so
// their latency overlaps. Block-local counting sort in LDS, one atomic bump
// per bucket per block, fully coalesced run writes.
__global__ __launch_bounds__(TPB_PREP) void prep_kernel(
    const float* __restrict__ x, const __half* __restrict__ Wh,
    const int* __restrict__ src, const int* __restrict__ dst,
    const int* __restrict__ widx,
    float* __restrict__ msgs, unsigned short* __restrict__ locs,
    int* __restrict__ gcnt, int E, int capE)
{
    __shared__ float          lmsg[PREP_EDGES];   // 16 KB
    __shared__ unsigned short lloc[PREP_EDGES];   //  8 KB
    __shared__ int hist[P2];
    __shared__ int lpre[P2];
    __shared__ int gbase[P2];

    const int tid = threadIdx.x;
    if (tid < P2) hist[tid] = 0;
    __syncthreads();

    const int e0 = blockIdx.x * PREP_EDGES;

    float msg[EPT];                 // computed message
    int   rnk[EPT];                 // rank within this block's bucket (-1 = inactive)
    int   pl[EPT];                  // packed (partition<<16) | local_dst

    const vint4* d4 = reinterpret_cast<const vint4*>(dst);
    const vint4* s4 = reinterpret_cast<const vint4*>(src);
    const vint4* w4 = reinterpret_cast<const vint4*>(widx);

    #pragma unroll
    for (int i = 0; i < EPT / 4; ++i) {
        int g4 = (e0 >> 2) + i * TPB_PREP + tid;
        int d_[4], s_[4], w_[4], act[4];
        if (g4 * 4 + 3 < E) {
            vint4 d = d4[g4], s = s4[g4], w = w4[g4];
            d_[0] = d.x; d_[1] = d.y; d_[2] = d.z; d_[3] = d.w;
            s_[0] = s.x; s_[1] = s.y; s_[2] = s.z; s_[3] = s.w;
            w_[0] = w.x; w_[1] = w.y; w_[2] = w.z; w_[3] = w.w;
            act[0] = act[1] = act[2] = act[3] = 1;
        } else {
            #pragma unroll
            for (int j = 0; j < 4; ++j) {
                int e = g4 * 4 + j;
                act[j] = (e < E);
                if (act[j]) { d_[j] = dst[e]; s_[j] = src[e]; w_[j] = widx[e]; }
                else        { d_[j] = 0;      s_[j] = 0;      w_[j] = 0; }
            }
        }
        #pragma unroll
        for (int j = 0; j < 4; ++j) {
            int k = i * 4 + j;
            if (act[j]) {
                // gathers issued here; consumed only after two barriers (scatter)
                msg[k] = __half2float(Wh[w_[j]]) * x[s_[j]];
                int p  = (int)((unsigned)d_[j] / NPP2);
                pl[k]  = (p << 16) | (d_[j] - p * NPP2);
                rnk[k] = atomicAdd(&hist[p], 1);
            } else {
                msg[k] = 0.f; pl[k] = 0; rnk[k] = -1;
            }
        }
    }
    __syncthreads();

    if (tid < P2) gbase[tid] = atomicAdd(&gcnt[tid], hist[tid]);
    if (tid == 0) {
        int run = 0;
        #pragma unroll
        for (int p = 0; p < P2; ++p) { lpre[p] = run; run += hist[p]; }
    }
    __syncthreads();

    // scatter into block-local sorted order (vmcnt wait for gathers lands here)
    #pragma unroll
    for (int k = 0; k < EPT; ++k) {
        if (rnk[k] >= 0) {
            int slot   = lpre[pl[k] >> 16] + rnk[k];
            lmsg[slot] = msg[k];
            lloc[slot] = (unsigned short)(pl[k] & 0xFFFF);
        }
    }
    __syncthreads();

    // coalesced write-out of P2 contiguous runs
    const int total = lpre[P2 - 1] + hist[P2 - 1];
    for (int s = tid; s < total; s += TPB_PREP) {
        int p = 0;
        #pragma unroll
        for (int q = 1; q < P2; ++q) p += (s >= lpre[q]);
        int gpos = gbase[p] + (s - lpre[p]);
        if (gpos < capE) {   // statistically unreachable with the cap margin
            size_t o = (size_t)p * capE + gpos;
            msgs[o] = lmsg[s];
            locs[o] = lloc[s];
        }
    }
}

// ---------------- Phase 2: dense branch-free LDS accumulation ----------------
// 10 partitions x 32 slices = 320 blocks; 80 KB LDS -> 2 blocks/CU (32 waves).
// Every lane active every instruction; static vmcnt counts -> pipelinable.
__global__ __launch_bounds__(TPB_SCAN2) void scan2_kernel(
    const float* __restrict__ msgs, const unsigned short* __restrict__ locs,
    const int* __restrict__ gcnt, float* __restrict__ partials, int capE)
{
    extern __shared__ float acc[];   // NPP2 floats = 80 KB
    const int tid = threadIdx.x;
    const int p = blockIdx.x % P2;
    const int k = blockIdx.x / P2;

    float4* z4 = reinterpret_cast<float4*>(acc);
    for (int i = tid; i < NPP2 / 4; i += TPB_SCAN2)
        z4[i] = make_float4(0.f, 0.f, 0.f, 0.f);
    __syncthreads();

    int count = gcnt[p];
    if (count > capE) count = capE;
    if (count < 0)    count = 0;

    long long ck0 = (long long)count * k;
    long long ck1 = (long long)count * (k + 1);
    int r0 = (k == 0) ? 0 : (int)((ck0 / KSLICES + 3) & ~3LL);
    int r1 = (k == KSLICES - 1) ? count : (int)((ck1 / KSLICES + 3) & ~3LL);
    if (r0 > count) r0 = count;
    if (r1 > count) r1 = count;

    const float*          M = msgs + (size_t)p * capE;
    const unsigned short* L = locs + (size_t)p * capE;

    int n4 = (r1 - r0) >> 2;
    const vfloat4*  M4 = reinterpret_cast<const vfloat4*>(M + r0);
    const vushort4* L4 = reinterpret_cast<const vushort4*>(L + r0);
    for (int i = tid; i < n4; i += TPB_SCAN2) {
        vfloat4  m = M4[i];
        vushort4 l = L4[i];
        atomicAdd(&acc[l.x], m.x);
        atomicAdd(&acc[l.y], m.y);
        atomicAdd(&acc[l.z], m.z);
        atomicAdd(&acc[l.w], m.w);
    }
    for (int e = r0 + n4 * 4 + tid; e < r1; e += TPB_SCAN2)
        atomicAdd(&acc[L[e]], M[e]);
    __syncthreads();

    float* out = partials + (size_t)k * PADDED_N + (size_t)p * NPP2;
    vfloat4* out4 = reinterpret_cast<vfloat4*>(out);
    const vfloat4* a4 = reinterpret_cast<const vfloat4*>(acc);
    for (int i = tid; i < NPP2 / 4; i += TPB_SCAN2)
        __builtin_nontemporal_store(a4[i], out4 + i);
}

// ---------------- Reduce: nslices slices + bias (shared by both paths) -------
__global__ __launch_bounds__(256) void reduceK_kernel(
    const float* __restrict__ partials, const float* __restrict__ bias,
    const int* __restrict__ label, float* __restrict__ y, int n, int nslices)
{
    int i = blockIdx.x * 256 + threadIdx.x;
    if (i >= n) return;
    float s0 = bias[label[i]];
    float s1 = 0.f, s2 = 0.f, s3 = 0.f;
    const float* p = partials + i;
    #pragma unroll 1
    for (int c = 0; c < nslices; c += 4) {
        s0 += __builtin_nontemporal_load(p + (size_t)(c + 0) * PADDED_N);
        s1 += __builtin_nontemporal_load(p + (size_t)(c + 1) * PADDED_N);
        s2 += __builtin_nontemporal_load(p + (size_t)(c + 2) * PADDED_N);
        s3 += __builtin_nontemporal_load(p + (size_t)(c + 3) * PADDED_N);
    }
    y[i] = (s0 + s1) + (s2 + s3);
}

// ---------------- Legacy fused + pipelined gather/scan (fallback) ------------
__global__ __launch_bounds__(TPB_SCAN) void fscan_kernel(
    const float* __restrict__ x, const __half* __restrict__ Wh,
    const int* __restrict__ src, const int* __restrict__ widx,
    const int* __restrict__ dst,
    float* __restrict__ partials, int E, int chunk)
{
    extern __shared__ float acc[];   // NPP floats = 160 KB
    int xcd = blockIdx.x % NXCD;
    int q   = blockIdx.x / NXCD;
    int p   = q % PARTS;
    int g   = q / PARTS;
    int c   = g * NXCD + xcd;

    float4* z4 = reinterpret_cast<float4*>(acc);
    for (int i = threadIdx.x; i < NPP / 4; i += TPB_SCAN)
        z4[i] = make_float4(0.f, 0.f, 0.f, 0.f);
    __syncthreads();

    int lo = c * chunk;
    int hi = min(E, lo + chunk);
    int base = p * NPP;

    const vint4* d4 = reinterpret_cast<const vint4*>(dst);
    const vint4* s4 = reinterpret_cast<const vint4*>(src);
    const vint4* w4 = reinterpret_cast<const vint4*>(widx);

    int ghi = hi / 4;
    int gi  = lo / 4 + threadIdx.x;

    unsigned rA0 = NPP, rA1 = NPP, rA2 = NPP, rA3 = NPP;
    float aA0 = 0.f, aA1 = 0.f, aA2 = 0.f, aA3 = 0.f;
    float bA0 = 0.f, bA1 = 0.f, bA2 = 0.f, bA3 = 0.f;
    bool haveA = (gi < ghi);
    if (haveA) {
        vint4 d = d4[gi], s = s4[gi], w = w4[gi];
        rA0 = (unsigned)(d.x - base); rA1 = (unsigned)(d.y - base);
        rA2 = (unsigned)(d.z - base); rA3 = (unsigned)(d.w - base);
        if (rA0 < NPP) { aA0 = __half2float(Wh[w.x]); bA0 = x[s.x]; }
        if (rA1 < NPP) { aA1 = __half2float(Wh[w.y]); bA1 = x[s.y]; }
        if (rA2 < NPP) { aA2 = __half2float(Wh[w.z]); bA2 = x[s.z]; }
        if (rA3 < NPP) { aA3 = __half2float(Wh[w.w]); bA3 = x[s.w]; }
    }

    while (haveA) {
        int gj = gi + TPB_SCAN;
        bool haveB = (gj < ghi);
        unsigned rB0 = NPP, rB1 = NPP, rB2 = NPP, rB3 = NPP;
        float aB0 = 0.f, aB1 = 0.f, aB2 = 0.f, aB3 = 0.f;
        float bB0 = 0.f, bB1 = 0.f, bB2 = 0.f, bB3 = 0.f;
        if (haveB) {
            vint4 d = d4[gj], s = s4[gj], w = w4[gj];
            rB0 = (unsigned)(d.x - base); rB1 = (unsigned)(d.y - base);
            rB2 = (unsigned)(d.z - base); rB3 = (unsigned)(d.w - base);
            if (rB0 < NPP) { aB0 = __half2float(Wh[w.x]); bB0 = x[s.x]; }
            if (rB1 < NPP) { aB1 = __half2float(Wh[w.y]); bB1 = x[s.y]; }
            if (rB2 < NPP) { aB2 = __half2float(Wh[w.z]); bB2 = x[s.z]; }
            if (rB3 < NPP) { aB3 = __half2float(Wh[w.w]); bB3 = x[s.w]; }
        }

        if (rA0 < NPP) atomicAdd(&acc[rA0], aA0 * bA0);
        if (rA1 < NPP) atomicAdd(&acc[rA1], aA1 * bA1);
        if (rA2 < NPP) atomicAdd(&acc[rA2], aA2 * bA2);
        if (rA3 < NPP) atomicAdd(&acc[rA3], aA3 * bA3);

        rA0 = rB0; rA1 = rB1; rA2 = rB2; rA3 = rB3;
        aA0 = aB0; aA1 = aB1; aA2 = aB2; aA3 = aB3;
        bA0 = bB0; bA1 = bB1; bA2 = bB2; bA3 = bB3;
        gi = gj; haveA = haveB;
    }
    __syncthreads();

    vfloat4* out4 = reinterpret_cast<vfloat4*>(partials + (size_t)c * PADDED_N + base);
    const vfloat4* av4 = reinterpret_cast<const vfloat4*>(acc);
    for (int i = threadIdx.x; i < NPP / 4; i += TPB_SCAN)
        __builtin_nontemporal_store(av4[i], out4 + i);
}

// ---------------- Fallback (direct atomics) if ws too small ----------------
__global__ __launch_bounds__(256) void bias_init_kernel(
    const float* __restrict__ Param_b, const int* __restrict__ node_label,
    float* __restrict__ y, int n_nodes)
{
    int i = blockIdx.x * blockDim.x + threadIdx.x;
    if (i < n_nodes) y[i] = Param_b[node_label[i]];
}

__global__ __launch_bounds__(256) void edge_scatter_kernel(
    const float* __restrict__ x, const float* __restrict__ Param_W,
    const int* __restrict__ src, const int* __restrict__ dst,
    const int* __restrict__ widx, float* __restrict__ y, int n_edges)
{
    int i = (blockIdx.x * blockDim.x + threadIdx.x) * 4;
    if (i + 3 < n_edges) {
        int4 s = *reinterpret_cast<const int4*>(src + i);
        int4 d = *reinterpret_cast<const int4*>(dst + i);
        int4 w = *reinterpret_cast<const int4*>(widx + i);
        unsafeAtomicAdd(&y[d.x], Param_W[w.x] * x[s.x]);
        unsafeAtomicAdd(&y[d.y], Param_W[w.y] * x[s.y]);
        unsafeAtomicAdd(&y[d.z], Param_W[w.z] * x[s.z]);
        unsafeAtomicAdd(&y[d.w], Param_W[w.w] * x[s.w]);
    } else {
        for (; i < n_edges; ++i)
            unsafeAtomicAdd(&y[dst[i]], Param_W[widx[i]] * x[src[i]]);
    }
}

extern "C" void kernel_launch(void* const* d_in, const int* in_sizes, int n_in,
                              void* d_out, int out_size, void* d_ws, size_t ws_size,
                              hipStream_t stream)
{
    const float* x          = (const float*)d_in[0];
    const float* Param_W    = (const float*)d_in[1];
    const float* Param_b    = (const float*)d_in[2];
    const int*   src        = (const int*)d_in[3];
    const int*   dst        = (const int*)d_in[4];
    const int*   weight_idx = (const int*)d_in[5];
    const int*   node_label = (const int*)d_in[6];
    float* y = (float*)d_out;

    int n_nodes = in_sizes[0];
    int W_n     = in_sizes[1];
    int E       = in_sizes[3];

    size_t wh_bytes = ((size_t)W_n * sizeof(__half) + 255) & ~(size_t)255;   // 2MB

    // ---- binned path sizing ----
    int capE = (((E / P2) + (E / P2) / 8 + 4096) & ~3);                       // ~1.44M
    size_t gcnt_bytes  = 256;
    size_t part2_bytes = (size_t)KSLICES * PADDED_N * sizeof(float);          // 26.2MB
    size_t msgs_bytes  = (((size_t)P2 * capE * sizeof(float)) + 255) & ~(size_t)255;
    size_t locs_bytes  = (((size_t)P2 * capE * sizeof(unsigned short)) + 255) & ~(size_t)255;
    size_t need2 = wh_bytes + gcnt_bytes + part2_bytes + msgs_bytes + locs_bytes;  // ~115MB

    // ---- legacy path sizing ----
    size_t part1_bytes = (size_t)NCHUNKS * PADDED_N * sizeof(float);          // 39.3MB
    size_t need1 = wh_bytes + part1_bytes;

    if (ws_size >= need2) {
        char* w = (char*)d_ws;
        __half* Wh        = (__half*)w;          w += wh_bytes;
        int*    gcnt      = (int*)w;             w += gcnt_bytes;
        float*  partials  = (float*)w;           w += part2_bytes;
        float*  msgs      = (float*)w;           w += msgs_bytes;
        unsigned short* locs = (unsigned short*)w;

        int t0 = (W_n + 3) / 4;
        wconv_kernel<<<(t0 + 255) / 256, 256, 0, stream>>>(Param_W, Wh, W_n, gcnt);

        int nbp = (E + PREP_EDGES - 1) / PREP_EDGES;
        if (nbp > 0)
            prep_kernel<<<nbp, TPB_PREP, 0, stream>>>(
                x, Wh, src, dst, weight_idx, msgs, locs, gcnt, E, capE);

        scan2_kernel<<<P2 * KSLICES, TPB_SCAN2, NPP2 * sizeof(float), stream>>>(
            msgs, locs, gcnt, partials, capE);

        reduceK_kernel<<<(n_nodes + 255) / 256, 256, 0, stream>>>(
            partials, Param_b, node_label, y, n_nodes, KSLICES);
    } else if (ws_size >= need1) {
        __half* Wh       = (__half*)d_ws;
        float*  partials = (float*)((char*)d_ws + wh_bytes);

        int t0 = (W_n + 3) / 4;
        wconv_kernel<<<(t0 + 255) / 256, 256, 0, stream>>>(Param_W, Wh, W_n, nullptr);

        int chunk = (((E + NCHUNKS - 1) / NCHUNKS) + 3) & ~3;
        fscan_kernel<<<PARTS * NCHUNKS, TPB_SCAN, NPP * sizeof(float), stream>>>(
            x, Wh, src, weight_idx, dst, partials, E, chunk);

        reduceK_kernel<<<(n_nodes + 255) / 256, 256, 0, stream>>>(
            partials, Param_b, node_label, y, n_nodes, NCHUNKS);
    } else {
        bias_init_kernel<<<(n_nodes + 255) / 256, 256, 0, stream>>>(
            Param_b, node_label, y, n_nodes);
        int t = (E + 3) / 4;
        edge_scatter_kernel<<<(t + 255) / 256, 256, 0, stream>>>(
            x, Param_W, src, dst, weight_idx, y, E);
    }
}

// Round 3
// 413.644 us; speedup vs baseline: 1.0183x; 1.0183x over previous
//
#include <hip/hip_runtime.h>
#include <hip/hip_fp16.h>

// ---------------- legacy fused-scan constants (fallback path) ----------------
#define PARTS 5
#define NPP 40960                  // 5*40960 = 204800 >= 200000
#define PADDED_N 204800            // == PARTS*NPP == P2*NPP2
#define NXCD 8
#define GRP 6
#define NCHUNKS (NXCD * GRP)       // 48
#define TPB_SCAN 1024

// ---------------- binned path constants ----------------
#define P2 10                      // dst partitions
#define NPP2 20480                 // nodes per partition; 10*20480 = 204800
#define KSLICES 32                 // slices (blocks) per partition
#define TPB_PREP 512
#define EPT 8                      // edges per thread in prep
#define PREP_EDGES (TPB_PREP * EPT)  // 4096 edges per prep block
#define TPB_SCAN2 1024

typedef int            vint4    __attribute__((ext_vector_type(4)));
typedef float          vfloat4  __attribute__((ext_vector_type(4)));
typedef unsigned short vushort4 __attribute__((ext_vector_type(4)));

// ---------------- Phase 0: W f32 -> f16 (2MB table => L2-resident gathers) ----
// Also zeroes the bucket counters for the binned path (ws re-poisoned each launch).
__global__ __launch_bounds__(256) void wconv_kernel(
    const float* __restrict__ W, __half* __restrict__ Wh, int n,
    int* __restrict__ gcnt)
{
    if (gcnt != nullptr && blockIdx.x == 0 && threadIdx.x < P2)
        gcnt[threadIdx.x] = 0;
    int i4 = (blockIdx.x * 256 + threadIdx.x) * 4;
    if (i4 + 3 < n) {
        vfloat4 w = *reinterpret_cast<const vfloat4*>(W + i4);
        __half2 h01 = __floats2half2_rn(w.x, w.y);
        __half2 h23 = __floats2half2_rn(w.z, w.w);
        *reinterpret_cast<__half2*>(Wh + i4)     = h01;
        *reinterpret_cast<__half2*>(Wh + i4 + 2) = h23;
    } else {
        for (; i4 < n; ++i4) Wh[i4] = __float2half(W[i4]);
    }
}

// ---------------- Phase 1: two-pass counting-sort into P2 buckets ------------
// r14 lesson: single-pass variant kept 24 per-edge values live across two
// barriers -> compiler spilled everything to scratch (VGPR_Count=24, 192us).
// Two-pass variant carries ZERO state across barriers: pass A builds the
// histogram from dst alone; pass B recomputes msg and claims its LDS slot via
// a per-bucket cursor atomic, consuming the value immediately. dst is read
// twice (L3-resident, +8us) in exchange for no scratch traffic.
__global__ __launch_bounds__(TPB_PREP) void prep_kernel(
    const float* __restrict__ x, const __half* __restrict__ Wh,
    const int* __restrict__ src, const int* __restrict__ dst,
    const int* __restrict__ widx,
    float* __restrict__ msgs, unsigned short* __restrict__ locs,
    int* __restrict__ gcnt, int E, int capE)
{
    __shared__ float          lmsg[PREP_EDGES];   // 16 KB
    __shared__ unsigned short lloc[PREP_EDGES];   //  8 KB
    __shared__ int hist[P2];
    __shared__ int lpre[P2];
    __shared__ int cur[P2];
    __shared__ int gbase[P2];

    const int tid = threadIdx.x;
    if (tid < P2) hist[tid] = 0;
    __syncthreads();

    const int e0 = blockIdx.x * PREP_EDGES;

    const vint4* d4 = reinterpret_cast<const vint4*>(dst);
    const vint4* s4 = reinterpret_cast<const vint4*>(src);
    const vint4* w4 = reinterpret_cast<const vint4*>(widx);

    // ---- pass A: histogram (dst only, no live state) ----
    #pragma unroll
    for (int i = 0; i < EPT / 4; ++i) {
        int g4 = (e0 >> 2) + i * TPB_PREP + tid;
        if (g4 * 4 + 3 < E) {
            vint4 d = d4[g4];
            atomicAdd(&hist[(unsigned)d.x / NPP2], 1);
            atomicAdd(&hist[(unsigned)d.y / NPP2], 1);
            atomicAdd(&hist[(unsigned)d.z / NPP2], 1);
            atomicAdd(&hist[(unsigned)d.w / NPP2], 1);
        } else {
            for (int e = g4 * 4; e < min(g4 * 4 + 4, E); ++e)
                atomicAdd(&hist[(unsigned)dst[e] / NPP2], 1);
        }
    }
    __syncthreads();

    if (tid < P2) gbase[tid] = atomicAdd(&gcnt[tid], hist[tid]);
    if (tid == 0) {
        int run = 0;
        #pragma unroll
        for (int p = 0; p < P2; ++p) { lpre[p] = run; cur[p] = run; run += hist[p]; }
    }
    __syncthreads();

    // ---- pass B: recompute msg, claim slot, stage into LDS (no live state) --
    #pragma unroll
    for (int i = 0; i < EPT / 4; ++i) {
        int g4 = (e0 >> 2) + i * TPB_PREP + tid;
        if (g4 * 4 + 3 < E) {
            vint4 d = d4[g4], s = s4[g4], w = w4[g4];
            // gathers for all 4 edges issued up front; slot atomics independent
            float m0 = __half2float(Wh[w.x]) * x[s.x];
            float m1 = __half2float(Wh[w.y]) * x[s.y];
            float m2 = __half2float(Wh[w.z]) * x[s.z];
            float m3 = __half2float(Wh[w.w]) * x[s.w];
            int p0 = (unsigned)d.x / NPP2, p1 = (unsigned)d.y / NPP2;
            int p2 = (unsigned)d.z / NPP2, p3 = (unsigned)d.w / NPP2;
            int t0 = atomicAdd(&cur[p0], 1);
            int t1 = atomicAdd(&cur[p1], 1);
            int t2 = atomicAdd(&cur[p2], 1);
            int t3 = atomicAdd(&cur[p3], 1);
            lmsg[t0] = m0; lloc[t0] = (unsigned short)(d.x - p0 * NPP2);
            lmsg[t1] = m1; lloc[t1] = (unsigned short)(d.y - p1 * NPP2);
            lmsg[t2] = m2; lloc[t2] = (unsigned short)(d.z - p2 * NPP2);
            lmsg[t3] = m3; lloc[t3] = (unsigned short)(d.w - p3 * NPP2);
        } else {
            for (int e = g4 * 4; e < min(g4 * 4 + 4, E); ++e) {
                float m = __half2float(Wh[widx[e]]) * x[src[e]];
                int p = (unsigned)dst[e] / NPP2;
                int t = atomicAdd(&cur[p], 1);
                lmsg[t] = m; lloc[t] = (unsigned short)(dst[e] - p * NPP2);
            }
        }
    }
    __syncthreads();

    // ---- coalesced write-out of P2 contiguous runs ----
    const int total = lpre[P2 - 1] + hist[P2 - 1];
    for (int s = tid; s < total; s += TPB_PREP) {
        int p = 0;
        #pragma unroll
        for (int q = 1; q < P2; ++q) p += (s >= lpre[q]);
        int gpos = gbase[p] + (s - lpre[p]);
        if (gpos < capE) {   // statistically unreachable with the cap margin
            size_t o = (size_t)p * capE + gpos;
            msgs[o] = lmsg[s];
            locs[o] = lloc[s];
        }
    }
}

// ---------------- Phase 2: dense branch-free LDS accumulation ----------------
// 10 partitions x 32 slices = 320 blocks; 80 KB LDS -> 2 blocks/CU (32 waves).
// r14 lesson: plain atomicAdd on shared float compiles to a CAS retry loop;
// unsafeAtomicAdd emits the native ds_add_f32 (no return, no retry).
__global__ __launch_bounds__(TPB_SCAN2) void scan2_kernel(
    const float* __restrict__ msgs, const unsigned short* __restrict__ locs,
    const int* __restrict__ gcnt, float* __restrict__ partials, int capE)
{
    extern __shared__ float acc[];   // NPP2 floats = 80 KB
    const int tid = threadIdx.x;
    const int p = blockIdx.x % P2;
    const int k = blockIdx.x / P2;

    float4* z4 = reinterpret_cast<float4*>(acc);
    for (int i = tid; i < NPP2 / 4; i += TPB_SCAN2)
        z4[i] = make_float4(0.f, 0.f, 0.f, 0.f);
    __syncthreads();

    int count = gcnt[p];
    if (count > capE) count = capE;
    if (count < 0)    count = 0;

    long long ck0 = (long long)count * k;
    long long ck1 = (long long)count * (k + 1);
    int r0 = (k == 0) ? 0 : (int)((ck0 / KSLICES + 3) & ~3LL);
    int r1 = (k == KSLICES - 1) ? count : (int)((ck1 / KSLICES + 3) & ~3LL);
    if (r0 > count) r0 = count;
    if (r1 > count) r1 = count;

    const float*          M = msgs + (size_t)p * capE;
    const unsigned short* L = locs + (size_t)p * capE;

    int n4 = (r1 - r0) >> 2;
    const vfloat4*  M4 = reinterpret_cast<const vfloat4*>(M + r0);
    const vushort4* L4 = reinterpret_cast<const vushort4*>(L + r0);
    for (int i = tid; i < n4; i += TPB_SCAN2) {
        vfloat4  m = M4[i];
        vushort4 l = L4[i];
        unsafeAtomicAdd(&acc[l.x], m.x);
        unsafeAtomicAdd(&acc[l.y], m.y);
        unsafeAtomicAdd(&acc[l.z], m.z);
        unsafeAtomicAdd(&acc[l.w], m.w);
    }
    for (int e = r0 + n4 * 4 + tid; e < r1; e += TPB_SCAN2)
        unsafeAtomicAdd(&acc[L[e]], M[e]);
    __syncthreads();

    float* out = partials + (size_t)k * PADDED_N + (size_t)p * NPP2;
    vfloat4* out4 = reinterpret_cast<vfloat4*>(out);
    const vfloat4* a4 = reinterpret_cast<const vfloat4*>(acc);
    for (int i = tid; i < NPP2 / 4; i += TPB_SCAN2)
        __builtin_nontemporal_store(a4[i], out4 + i);
}

// ---------------- Reduce: nslices slices + bias (shared by both paths) -------
__global__ __launch_bounds__(256) void reduceK_kernel(
    const float* __restrict__ partials, const float* __restrict__ bias,
    const int* __restrict__ label, float* __restrict__ y, int n, int nslices)
{
    int i = blockIdx.x * 256 + threadIdx.x;
    if (i >= n) return;
    float s0 = bias[label[i]];
    float s1 = 0.f, s2 = 0.f, s3 = 0.f;
    const float* p = partials + i;
    #pragma unroll 1
    for (int c = 0; c < nslices; c += 4) {
        s0 += __builtin_nontemporal_load(p + (size_t)(c + 0) * PADDED_N);
        s1 += __builtin_nontemporal_load(p + (size_t)(c + 1) * PADDED_N);
        s2 += __builtin_nontemporal_load(p + (size_t)(c + 2) * PADDED_N);
        s3 += __builtin_nontemporal_load(p + (size_t)(c + 3) * PADDED_N);
    }
    y[i] = (s0 + s1) + (s2 + s3);
}

// ---------------- Legacy fused + pipelined gather/scan (fallback) ------------
__global__ __launch_bounds__(TPB_SCAN) void fscan_kernel(
    const float* __restrict__ x, const __half* __restrict__ Wh,
    const int* __restrict__ src, const int* __restrict__ widx,
    const int* __restrict__ dst,
    float* __restrict__ partials, int E, int chunk)
{
    extern __shared__ float acc[];   // NPP floats = 160 KB
    int xcd = blockIdx.x % NXCD;
    int q   = blockIdx.x / NXCD;
    int p   = q % PARTS;
    int g   = q / PARTS;
    int c   = g * NXCD + xcd;

    float4* z4 = reinterpret_cast<float4*>(acc);
    for (int i = threadIdx.x; i < NPP / 4; i += TPB_SCAN)
        z4[i] = make_float4(0.f, 0.f, 0.f, 0.f);
    __syncthreads();

    int lo = c * chunk;
    int hi = min(E, lo + chunk);
    int base = p * NPP;

    const vint4* d4 = reinterpret_cast<const vint4*>(dst);
    const vint4* s4 = reinterpret_cast<const vint4*>(src);
    const vint4* w4 = reinterpret_cast<const vint4*>(widx);

    int ghi = hi / 4;
    int gi  = lo / 4 + threadIdx.x;

    unsigned rA0 = NPP, rA1 = NPP, rA2 = NPP, rA3 = NPP;
    float aA0 = 0.f, aA1 = 0.f, aA2 = 0.f, aA3 = 0.f;
    float bA0 = 0.f, bA1 = 0.f, bA2 = 0.f, bA3 = 0.f;
    bool haveA = (gi < ghi);
    if (haveA) {
        vint4 d = d4[gi], s = s4[gi], w = w4[gi];
        rA0 = (unsigned)(d.x - base); rA1 = (unsigned)(d.y - base);
        rA2 = (unsigned)(d.z - base); rA3 = (unsigned)(d.w - base);
        if (rA0 < NPP) { aA0 = __half2float(Wh[w.x]); bA0 = x[s.x]; }
        if (rA1 < NPP) { aA1 = __half2float(Wh[w.y]); bA1 = x[s.y]; }
        if (rA2 < NPP) { aA2 = __half2float(Wh[w.z]); bA2 = x[s.z]; }
        if (rA3 < NPP) { aA3 = __half2float(Wh[w.w]); bA3 = x[s.w]; }
    }

    while (haveA) {
        int gj = gi + TPB_SCAN;
        bool haveB = (gj < ghi);
        unsigned rB0 = NPP, rB1 = NPP, rB2 = NPP, rB3 = NPP;
        float aB0 = 0.f, aB1 = 0.f, aB2 = 0.f, aB3 = 0.f;
        float bB0 = 0.f, bB1 = 0.f, bB2 = 0.f, bB3 = 0.f;
        if (haveB) {
            vint4 d = d4[gj], s = s4[gj], w = w4[gj];
            rB0 = (unsigned)(d.x - base); rB1 = (unsigned)(d.y - base);
            rB2 = (unsigned)(d.z - base); rB3 = (unsigned)(d.w - base);
            if (rB0 < NPP) { aB0 = __half2float(Wh[w.x]); bB0 = x[s.x]; }
            if (rB1 < NPP) { aB1 = __half2float(Wh[w.y]); bB1 = x[s.y]; }
            if (rB2 < NPP) { aB2 = __half2float(Wh[w.z]); bB2 = x[s.z]; }
            if (rB3 < NPP) { aB3 = __half2float(Wh[w.w]); bB3 = x[s.w]; }
        }

        if (rA0 < NPP) unsafeAtomicAdd(&acc[rA0], aA0 * bA0);
        if (rA1 < NPP) unsafeAtomicAdd(&acc[rA1], aA1 * bA1);
        if (rA2 < NPP) unsafeAtomicAdd(&acc[rA2], aA2 * bA2);
        if (rA3 < NPP) unsafeAtomicAdd(&acc[rA3], aA3 * bA3);

        rA0 = rB0; rA1 = rB1; rA2 = rB2; rA3 = rB3;
        aA0 = aB0; aA1 = aB1; aA2 = aB2; aA3 = aB3;
        bA0 = bB0; bA1 = bB1; bA2 = bB2; bA3 = bB3;
        gi = gj; haveA = haveB;
    }
    __syncthreads();

    vfloat4* out4 = reinterpret_cast<vfloat4*>(partials + (size_t)c * PADDED_N + base);
    const vfloat4* av4 = reinterpret_cast<const vfloat4*>(acc);
    for (int i = threadIdx.x; i < NPP / 4; i += TPB_SCAN)
        __builtin_nontemporal_store(av4[i], out4 + i);
}

// ---------------- Fallback (direct atomics) if ws too small ----------------
__global__ __launch_bounds__(256) void bias_init_kernel(
    const float* __restrict__ Param_b, const int* __restrict__ node_label,
    float* __restrict__ y, int n_nodes)
{
    int i = blockIdx.x * blockDim.x + threadIdx.x;
    if (i < n_nodes) y[i] = Param_b[node_label[i]];
}

__global__ __launch_bounds__(256) void edge_scatter_kernel(
    const float* __restrict__ x, const float* __restrict__ Param_W,
    const int* __restrict__ src, const int* __restrict__ dst,
    const int* __restrict__ widx, float* __restrict__ y, int n_edges)
{
    int i = (blockIdx.x * blockDim.x + threadIdx.x) * 4;
    if (i + 3 < n_edges) {
        int4 s = *reinterpret_cast<const int4*>(src + i);
        int4 d = *reinterpret_cast<const int4*>(dst + i);
        int4 w = *reinterpret_cast<const int4*>(widx + i);
        unsafeAtomicAdd(&y[d.x], Param_W[w.x] * x[s.x]);
        unsafeAtomicAdd(&y[d.y], Param_W[w.y] * x[s.y]);
        unsafeAtomicAdd(&y[d.z], Param_W[w.z] * x[s.z]);
        unsafeAtomicAdd(&y[d.w], Param_W[w.w] * x[s.w]);
    } else {
        for (; i < n_edges; ++i)
            unsafeAtomicAdd(&y[dst[i]], Param_W[widx[i]] * x[src[i]]);
    }
}

extern "C" void kernel_launch(void* const* d_in, const int* in_sizes, int n_in,
                              void* d_out, int out_size, void* d_ws, size_t ws_size,
                              hipStream_t stream)
{
    const float* x          = (const float*)d_in[0];
    const float* Param_W    = (const float*)d_in[1];
    const float* Param_b    = (const float*)d_in[2];
    const int*   src        = (const int*)d_in[3];
    const int*   dst        = (const int*)d_in[4];
    const int*   weight_idx = (const int*)d_in[5];
    const int*   node_label = (const int*)d_in[6];
    float* y = (float*)d_out;

    int n_nodes = in_sizes[0];
    int W_n     = in_sizes[1];
    int E       = in_sizes[3];

    size_t wh_bytes = ((size_t)W_n * sizeof(__half) + 255) & ~(size_t)255;   // 2MB

    // ---- binned path sizing ----
    int capE = (((E / P2) + (E / P2) / 8 + 4096) & ~3);                       // ~1.44M
    size_t gcnt_bytes  = 256;
    size_t part2_bytes = (size_t)KSLICES * PADDED_N * sizeof(float);          // 26.2MB
    size_t msgs_bytes  = (((size_t)P2 * capE * sizeof(float)) + 255) & ~(size_t)255;
    size_t locs_bytes  = (((size_t)P2 * capE * sizeof(unsigned short)) + 255) & ~(size_t)255;
    size_t need2 = wh_bytes + gcnt_bytes + part2_bytes + msgs_bytes + locs_bytes;  // ~115MB

    // ---- legacy path sizing ----
    size_t part1_bytes = (size_t)NCHUNKS * PADDED_N * sizeof(float);          // 39.3MB
    size_t need1 = wh_bytes + part1_bytes;

    if (ws_size >= need2) {
        char* w = (char*)d_ws;
        __half* Wh        = (__half*)w;          w += wh_bytes;
        int*    gcnt      = (int*)w;             w += gcnt_bytes;
        float*  partials  = (float*)w;           w += part2_bytes;
        float*  msgs      = (float*)w;           w += msgs_bytes;
        unsigned short* locs = (unsigned short*)w;

        int t0 = (W_n + 3) / 4;
        wconv_kernel<<<(t0 + 255) / 256, 256, 0, stream>>>(Param_W, Wh, W_n, gcnt);

        int nbp = (E + PREP_EDGES - 1) / PREP_EDGES;
        if (nbp > 0)
            prep_kernel<<<nbp, TPB_PREP, 0, stream>>>(
                x, Wh, src, dst, weight_idx, msgs, locs, gcnt, E, capE);

        scan2_kernel<<<P2 * KSLICES, TPB_SCAN2, NPP2 * sizeof(float), stream>>>(
            msgs, locs, gcnt, partials, capE);

        reduceK_kernel<<<(n_nodes + 255) / 256, 256, 0, stream>>>(
            partials, Param_b, node_label, y, n_nodes, KSLICES);
    } else if (ws_size >= need1) {
        __half* Wh       = (__half*)d_ws;
        float*  partials = (float*)((char*)d_ws + wh_bytes);

        int t0 = (W_n + 3) / 4;
        wconv_kernel<<<(t0 + 255) / 256, 256, 0, stream>>>(Param_W, Wh, W_n, nullptr);

        int chunk = (((E + NCHUNKS - 1) / NCHUNKS) + 3) & ~3;
        fscan_kernel<<<PARTS * NCHUNKS, TPB_SCAN, NPP * sizeof(float), stream>>>(
            x, Wh, src, weight_idx, dst, partials, E, chunk);

        reduceK_kernel<<<(n_nodes + 255) / 256, 256, 0, stream>>>(
            partials, Param_b, node_label, y, n_nodes, NCHUNKS);
    } else {
        bias_init_kernel<<<(n_nodes + 255) / 256, 256, 0, stream>>>(
            Param_b, node_label, y, n_nodes);
        int t = (E + 3) / 4;
        edge_scatter_kernel<<<(t + 255) / 256, 256, 0, stream>>>(
            x, Param_W, src, dst, weight_idx, y, E);
    }
}